// Round 3
// baseline (190.939 us; speedup 1.0000x reference)
//
#include <hip/hip_runtime.h>
#include <hip/hip_fp16.h>

#define N_PTS 100000
#define MU_F  100.0f

typedef unsigned int uint;
typedef _Float16 h2 __attribute__((ext_vector_type(2)));
typedef float f2 __attribute__((ext_vector_type(2)));

#define E_SCALE 16384.0f
#define E_SCALE_INV (1.0f / 16384.0f)

static __device__ inline h2 h2pack(float a, float b) {
    return __builtin_bit_cast(h2, __builtin_amdgcn_cvt_pkrtz(a, b));
}
static __device__ inline float fdot2f(h2 a, h2 b, float c) {
    return __builtin_amdgcn_fdot2(a, b, c, false);
}
static __device__ inline h2 h2fma(h2 a, h2 b, h2 c) {
#if __has_builtin(__builtin_elementwise_fma)
    return __builtin_elementwise_fma(a, b, c);
#else
    return a * b + c;
#endif
}
static __device__ inline h2 h2max(h2 a, h2 b) {
#if __has_builtin(__builtin_elementwise_max)
    return __builtin_elementwise_max(a, b);
#else
    h2 r;
    r.x = a.x > b.x ? a.x : b.x;
    r.y = a.y > b.y ? a.y : b.y;
    return r;
#endif
}

// ---------------------------------------------------------------------------
// K1: encode only (counting sort deleted — K2/K4 run in natural point order
// with a per-block LDS invC table instead of per-cluster register tables).
// ---------------------------------------------------------------------------
#define ENC_BLKS 256
#define TR_BLKS  1563            // ceil(100000/64), appended to K2's grid
#define S_BLKS   1024
#define NPAIRS   (N_PTS / 2)     // 50000 (N even -> all pairs full)
#define S_CH     ((NPAIRS + S_BLKS - 1) / S_BLKS)   // 49
#define M_BLKS   1024
#define M_CH     ((NPAIRS + M_BLKS - 1) / M_BLKS)   // 49

__global__ __launch_bounds__(256) void k_prep(const float* __restrict__ x,
                                              const float* __restrict__ encW,
                                              const float* __restrict__ encB,
                                              float* __restrict__ enc) {
    int b = blockIdx.x;
    // ----- encode: enc[row] = x . encW[row,:] + encB[row]
    int row = b & 31;
    int chunk = b >> 5;              // 0..7
    const int CH = N_PTS / 8;        // 12500
    int base = chunk * CH;
    const float4* W4 = reinterpret_cast<const float4*>(encW + (size_t)row * N_PTS + base);
    const float4* x4 = reinterpret_cast<const float4*>(x + base);
    const int nv = CH / 4;           // 3125
    float acc = 0.f;
    for (int idx = threadIdx.x; idx < nv; idx += 256) {
        float4 w = W4[idx];
        float4 xv = x4[idx];
        acc += w.x * xv.x + w.y * xv.y + w.z * xv.z + w.w * xv.w;
    }
    #pragma unroll
    for (int off = 32; off > 0; off >>= 1) acc += __shfl_down(acc, off);
    __shared__ float sred[4];
    int wid = threadIdx.x >> 6;
    if ((threadIdx.x & 63) == 0) sred[wid] = acc;
    __syncthreads();
    if (threadIdx.x == 0) {
        float s = sred[0] + sred[1] + sred[2] + sred[3];
        if (chunk == 0) s += encB[row];
        atomicAdd(enc + row, s);
    }
}

// ---------------------------------------------------------------------------
// helper: build full invC table in LDS: invF[c*32 + i] = 1/(sigmoid*MU/60)^2
// (512 sigmoid rows; bw row r = i*16 + c)
// ---------------------------------------------------------------------------
__device__ inline void build_invF(const float* __restrict__ encL,
                                  const float* __restrict__ bw_w,
                                  const float* __restrict__ bw_b,
                                  float* __restrict__ invF) {
    for (int r = threadIdx.x; r < 512; r += 256) {
        int i = r >> 4, c = r & 15;
        float z = bw_b[r];
        const float* wr = bw_w + r * 32;
        #pragma unroll
        for (int p = 0; p < 32; ++p) z = fmaf(encL[p], wr[p], z);
        float s = 1.f / (1.f + __expf(-z));
        float wmu = s * (MU_F / 60.0f);
        invF[c * 32 + i] = 1.f / (wmu * wmu);
    }
}

// ---------------------------------------------------------------------------
// K2: blocks [0,1024): S partials, natural point order. All addresses are
//     linear in the loop index (no perm gather chain); per-point cluster
//     coefficients come from broadcast ds_read_b128 of the LDS invC table.
//     blocks [1024,2587): dec [32,N] f32 -> decT [N,32] fp16 transpose.
// ---------------------------------------------------------------------------
__global__ __launch_bounds__(256, 4) void k_S(const float* __restrict__ enc_g,
                                              const float* __restrict__ bw_w,
                                              const float* __restrict__ bw_b,
                                              const float* __restrict__ nd,
                                              const int* __restrict__ labels,
                                              float* __restrict__ S,
                                              float* __restrict__ S_part,
                                              const float* __restrict__ dec,
                                              __half* __restrict__ decT) {
    int b = blockIdx.x;
    if (b >= S_BLKS) {
        // ----- transpose dec [32,N] f32 -> decT [N,32] fp16 (64B rows)
        __shared__ float tile[32][65];
        int j0 = (b - S_BLKS) * 64;
        int col = threadIdx.x & 63;
        int r0 = threadIdx.x >> 6;       // 0..3
        #pragma unroll
        for (int it = 0; it < 8; ++it) {
            int row = it * 4 + r0;
            int j = j0 + col;
            float v = (j < N_PTS) ? dec[(size_t)row * N_PTS + j] : 0.f;
            tile[row][col] = v;
        }
        __syncthreads();
        #pragma unroll
        for (int it = 0; it < 4; ++it) {
            int idx = it * 256 + threadIdx.x;
            int j = idx >> 4;            // 0..63
            int p = idx & 15;            // i-pair
            int jj = j0 + j;
            if (jj < N_PTS) {
                __half2 h = __halves2half2(__float2half(tile[2 * p][j]),
                                           __float2half(tile[2 * p + 1][j]));
                *reinterpret_cast<__half2*>(decT + (size_t)jj * 32 + 2 * p) = h;
            }
        }
        return;
    }

    __shared__ float encL[32];
    __shared__ float invF[512];
    __shared__ float Sloc[1024];
    if (threadIdx.x < 32) encL[threadIdx.x] = enc_g[threadIdx.x];
    for (int t = threadIdx.x; t < 1024; t += 256) Sloc[t] = 0.f;
    __syncthreads();
    build_invF(encL, bw_w, bw_b, invF);
    __syncthreads();

    int lane = threadIdx.x & 63;
    int kk = lane & 31;
    int jh = lane >> 5;
    int w = threadIdx.x >> 6;            // wave 0..3
    int start = b * S_CH;
    int pend = min(start + S_CH, NPAIRS);
    int p = start + w;

    f2 acc2[16];
    #pragma unroll
    for (int t = 0; t < 16; ++t) { acc2[t].x = 0.f; acc2[t].y = 0.f; }

    if (p < pend) {
        auto ld = [&](int pc, float& d, int& c) {
            pc = min(pc, NPAIRS - 1);
            int j = 2 * pc + jh;
            d = nd[(size_t)j * 32 + kk];
            c = labels[j];
        };
        float dA, dB; int cA, cB;
        ld(p, dA, cA);
        ld(p + 4, dB, cB);
        f2 onev; onev.x = 1.f; onev.y = 1.f;
        while (p < pend) {
            float dC; int cC;
            ld(p + 8, dC, cC);
            float d2 = dA * dA;
            f2 md2; md2.x = -d2; md2.y = -d2;
            const float4* ivp = reinterpret_cast<const float4*>(&invF[cA * 32]);
            #pragma unroll
            for (int t4 = 0; t4 < 8; ++t4) {
                float4 iv = ivp[t4];         // ds_read_b128, broadcast per half-wave
                f2 i01; i01.x = iv.x; i01.y = iv.y;
                f2 i23; i23.x = iv.z; i23.y = iv.w;
                f2 w0 = md2 * i01 + onev;    // v_pk_fma_f32
                w0.x = fmaxf(w0.x, 0.f);
                w0.y = fmaxf(w0.y, 0.f);
                acc2[2 * t4] += w0;
                f2 w1 = md2 * i23 + onev;
                w1.x = fmaxf(w1.x, 0.f);
                w1.y = fmaxf(w1.y, 0.f);
                acc2[2 * t4 + 1] += w1;
            }
            dA = dB; cA = cB; dB = dC; cB = cC;
            p += 4;
        }
    }
    #pragma unroll
    for (int t = 0; t < 16; ++t) {
        acc2[t].x += __shfl_xor(acc2[t].x, 32);
        acc2[t].y += __shfl_xor(acc2[t].y, 32);
    }
    if (jh == 0) {
        #pragma unroll
        for (int t = 0; t < 16; ++t) {
            atomicAdd(&Sloc[(2 * t) * 32 + kk], acc2[t].x);
            atomicAdd(&Sloc[(2 * t + 1) * 32 + kk], acc2[t].y);
        }
    }
    __syncthreads();
    if (S_part) {
        for (int t = threadIdx.x; t < 1024; t += 256)
            S_part[(size_t)b * 1024 + t] = Sloc[t];
    } else {
        for (int t = threadIdx.x; t < 1024; t += 256) {
            float v = Sloc[t];
            if (v != 0.f) atomicAdd(&S[t], v);
        }
    }
}

// ---------------------------------------------------------------------------
// K3: reduce S_part (1024 x 1024) into S (pre-zeroed). grid 64 x 1024.
// ---------------------------------------------------------------------------
__global__ __launch_bounds__(1024) void k_S_reduce(const float* __restrict__ S_part,
                                                   float* __restrict__ S) {
    int g = blockIdx.x;                  // 0..63
    int t = threadIdx.x;                 // 0..1023
    float s = 0.f;
    #pragma unroll
    for (int u = 0; u < 16; ++u)
        s += S_part[(size_t)(g * 16 + u) * 1024 + t];
    atomicAdd(&S[t], s);
}

// ---------------------------------------------------------------------------
// K4 (main): natural point order. nid/nd/labels addresses are linear in the
// loop index; the only remaining gather is decT (1 level, pipelined 1 iter
// ahead). Per-pair cluster coefficients invh come from a 1KB LDS table
// invHL[c][q][t] via one ds_read_b128 per point. Quad-broadcast layout:
// lane L: R=L>>2 (element 0..15), q=L&3 (16B quad of 64B decT row).
// ---------------------------------------------------------------------------
__global__ __launch_bounds__(256, 4) void k_main(const float* __restrict__ enc_g,
                                                 const float* __restrict__ bw_w,
                                                 const float* __restrict__ bw_b,
                                                 const float* __restrict__ S_g,
                                                 const float* __restrict__ nd,
                                                 const int* __restrict__ nid,
                                                 const int* __restrict__ labels,
                                                 const __half* __restrict__ decT,
                                                 float* __restrict__ out) {
    __shared__ float encL[32];
    __shared__ float invF[512];
    __shared__ float ELf[1024];          // E[i][kk] * E_SCALE
    __shared__ h2 invHL[256];            // [c][q][t] : c*16 + q*4 + t

    if (threadIdx.x < 32) encL[threadIdx.x] = enc_g[threadIdx.x];
    __syncthreads();
    build_invF(encL, bw_w, bw_b, invF);
    for (int t = threadIdx.x; t < 1024; t += 256)
        ELf[t] = encL[t >> 5] / S_g[t] * E_SCALE;
    __syncthreads();
    {
        int t = threadIdx.x;             // 0..255 == 16c x 4q x 4t
        int c = t >> 4, q = (t >> 2) & 3, tt = t & 3;
        int i0 = q * 8 + 2 * tt;
        invHL[t] = h2pack(fminf(invF[c * 32 + i0], 6.0e4f),
                          fminf(invF[c * 32 + i0 + 1], 6.0e4f));
    }
    __syncthreads();

    int lane = threadIdx.x & 63;
    int R = lane >> 2;                   // 0..15
    int q = lane & 3;                    // i-quarter / row quad

    h2 EhA[4], EhB[4];
    #pragma unroll
    for (int t = 0; t < 4; ++t) {
        int i0 = q * 8 + 2 * t;
        EhA[t] = h2pack(ELf[i0 * 32 + R], ELf[(i0 + 1) * 32 + R]);
        EhB[t] = h2pack(ELf[i0 * 32 + R + 16], ELf[(i0 + 1) * 32 + R + 16]);
    }
    const h2 zero2 = h2pack(0.f, 0.f);
    const h2 one2 = h2pack(1.f, 1.f);

    int w = threadIdx.x >> 6;            // wave 0..3
    int start = blockIdx.x * M_CH;
    int pend = min(start + M_CH, NPAIRS);
    int pa = start + w;
    const uint4* decQ = reinterpret_cast<const uint4*>(decT);
    if (pa >= pend) return;

    auto load_ldd = [&](int pc, int* id, float* dd, int& c0, int& c1) {
        pc = min(pc, NPAIRS - 1);
        int j0 = 2 * pc, j1 = j0 + 1;
        #pragma unroll
        for (int s = 0; s < 4; ++s) {
            size_t idx = (size_t)((s >> 1) ? j1 : j0) * 32 + (s & 1) * 16 + R;
            id[s] = nid[idx];
            dd[s] = nd[idx];
        }
        c0 = labels[j0];
        c1 = labels[j1];
    };
    auto load_rows = [&](const int* id, uint4* r) {
        #pragma unroll
        for (int s = 0; s < 4; ++s)
            r[s] = decQ[(size_t)id[s] * 4 + q];
    };
    auto load_ih = [&](int c0, int c1, h2* ih0, h2* ih1) {
        uint4 a = *reinterpret_cast<const uint4*>(&invHL[c0 * 16 + q * 4]);
        uint4 bq = *reinterpret_cast<const uint4*>(&invHL[c1 * 16 + q * 4]);
        ih0[0] = __builtin_bit_cast(h2, a.x);  ih0[1] = __builtin_bit_cast(h2, a.y);
        ih0[2] = __builtin_bit_cast(h2, a.z);  ih0[3] = __builtin_bit_cast(h2, a.w);
        ih1[0] = __builtin_bit_cast(h2, bq.x); ih1[1] = __builtin_bit_cast(h2, bq.y);
        ih1[2] = __builtin_bit_cast(h2, bq.z); ih1[3] = __builtin_bit_cast(h2, bq.w);
    };

    // pipeline: A = compute, B = rows+ih being fetched, C = ids/dd/labels load
    int ida[4], idb[4]; float dda[4], ddb[4];
    int ca0, ca1, cb0, cb1;
    uint4 ra[4], rb[4];
    h2 ihA0[4], ihA1[4];

    load_ldd(pa, ida, dda, ca0, ca1);
    load_ldd(pa + 4, idb, ddb, cb0, cb1);
    load_rows(ida, ra);
    load_ih(ca0, ca1, ihA0, ihA1);

    while (pa < pend) {
        // issue next-stage memory ops before the compute
        load_rows(idb, rb);
        h2 ihB0[4], ihB1[4];
        load_ih(cb0, cb1, ihB0, ihB1);
        int idc[4]; float ddc[4]; int cc0, cc1;
        load_ldd(pa + 8, idc, ddc, cc0, cc1);

        float d20 = dda[0] * dda[0];
        float d21 = dda[1] * dda[1];
        float d22 = dda[2] * dda[2];
        float d23 = dda[3] * dda[3];
        h2 md0 = h2pack(-d20, -d20);
        h2 md1 = h2pack(-d21, -d21);
        h2 md2 = h2pack(-d22, -d22);
        h2 md3 = h2pack(-d23, -d23);

        float a0 = 0.f, a1 = 0.f, a2 = 0.f, a3 = 0.f;
        #pragma unroll
        for (int t = 0; t < 4; ++t) {
            uint dw0 = (t == 0) ? ra[0].x : (t == 1) ? ra[0].y : (t == 2) ? ra[0].z : ra[0].w;
            uint dw1 = (t == 0) ? ra[1].x : (t == 1) ? ra[1].y : (t == 2) ? ra[1].z : ra[1].w;
            uint dw2 = (t == 0) ? ra[2].x : (t == 1) ? ra[2].y : (t == 2) ? ra[2].z : ra[2].w;
            uint dw3 = (t == 0) ? ra[3].x : (t == 1) ? ra[3].y : (t == 2) ? ra[3].z : ra[3].w;
            {
                h2 wv = h2max(h2fma(md0, ihA0[t], one2), zero2);
                a0 = fdot2f(wv * EhA[t], __builtin_bit_cast(h2, dw0), a0);
            }
            {
                h2 wv = h2max(h2fma(md1, ihA0[t], one2), zero2);
                a1 = fdot2f(wv * EhB[t], __builtin_bit_cast(h2, dw1), a1);
            }
            {
                h2 wv = h2max(h2fma(md2, ihA1[t], one2), zero2);
                a2 = fdot2f(wv * EhA[t], __builtin_bit_cast(h2, dw2), a2);
            }
            {
                h2 wv = h2max(h2fma(md3, ihA1[t], one2), zero2);
                a3 = fdot2f(wv * EhB[t], __builtin_bit_cast(h2, dw3), a3);
            }
        }
        float u = a0 + a1;               // j0 partial
        float v = a2 + a3;               // j1 partial
        #pragma unroll
        for (int off = 32; off > 0; off >>= 1) {
            u += __shfl_xor(u, off);
            v += __shfl_xor(v, off);
        }
        if (lane == 0)  out[2 * pa]     = u * E_SCALE_INV;
        if (lane == 32) out[2 * pa + 1] = v * E_SCALE_INV;

        // shift pipeline
        ca0 = cb0; ca1 = cb1; cb0 = cc0; cb1 = cc1;
        #pragma unroll
        for (int s = 0; s < 4; ++s) {
            dda[s] = ddb[s]; ddb[s] = ddc[s];
            ida[s] = idb[s]; idb[s] = idc[s];
            ra[s] = rb[s];
            ihA0[s] = ihB0[s]; ihA1[s] = ihB1[s];
        }
        pa += 4;
    }
}

// ---------------------------------------------------------------------------
extern "C" void kernel_launch(void* const* d_in, const int* in_sizes, int n_in,
                              void* d_out, int out_size, void* d_ws, size_t ws_size,
                              hipStream_t stream) {
    const float* x     = (const float*)d_in[0];
    const float* enc_w = (const float*)d_in[1];
    const float* enc_b = (const float*)d_in[2];
    const float* dec   = (const float*)d_in[3];
    const float* bw_w  = (const float*)d_in[4];
    const float* bw_b  = (const float*)d_in[5];
    const float* nd    = (const float*)d_in[6];
    const int*   nid   = (const int*)d_in[7];
    const int*   labels= (const int*)d_in[8];
    float* out = (float*)d_out;

    // ws layout:
    //   [0,128)              enc (32 f)
    //   [128,4224)           S (1024 f)
    //   [532480,6932480)     decT (N*32 fp16, 6.4 MB)
    //   [6932480,11126784)   S_part (1024*1024 f, 4 MB)  [if ws permits]
    char* ws = (char*)d_ws;
    float* enc    = (float*)(ws + 0);
    float* S      = (float*)(ws + 128);
    __half* decT  = (__half*)(ws + 532480);
    bool use_part = ws_size >= 11126784ull;
    float* S_part = use_part ? (float*)(ws + 6932480) : nullptr;

    (void)hipMemsetAsync(d_ws, 0, 4224, stream);    // enc, S
    k_prep<<<dim3(ENC_BLKS), dim3(256), 0, stream>>>(x, enc_w, enc_b, enc);
    k_S<<<dim3(S_BLKS + TR_BLKS), dim3(256), 0, stream>>>(
        enc, bw_w, bw_b, nd, labels, S, S_part, dec, decT);
    if (use_part)
        k_S_reduce<<<dim3(64), dim3(1024), 0, stream>>>(S_part, S);
    k_main<<<dim3(M_BLKS), dim3(256), 0, stream>>>(enc, bw_w, bw_b, S, nd, nid,
                                                   labels, decT, out);
}